// Round 1
// baseline (1161.047 us; speedup 1.0000x reference)
//
#include <hip/hip_runtime.h>
#include <hip/hip_bf16.h>
#include <stdint.h>

#define BROWS 2048
#define DIM   256
#define NS    100000
#define NPAD  100096        // 782 * 128
#define EPS   1e-12f

#define BM 128
#define BN 128
#define BK 32

typedef __attribute__((ext_vector_type(8))) short bf16x8;   // 8 bf16 = 4 VGPRs
typedef __attribute__((ext_vector_type(4))) float f32x4;

// round-to-nearest-even fp32 -> bf16
__device__ __forceinline__ unsigned short f2bf(float f) {
    union { float f; unsigned int u; } v; v.f = f;
    unsigned int u = v.u;
    u += ((u >> 16) & 1u) + 0x7FFFu;
    return (unsigned short)(u >> 16);
}

#define ASYNC_COPY16(gsrc, ldst)                                                   \
    __builtin_amdgcn_global_load_lds(                                              \
        (const __attribute__((address_space(1))) void*)(gsrc),                     \
        (__attribute__((address_space(3))) void*)(ldst), 16, 0, 0)

// ---------------------------------------------------------------------------
// Kernel 1: row-normalize x [2048,256] fp32 -> xn bf16.  One wave per row.
// ---------------------------------------------------------------------------
__global__ __launch_bounds__(64)
void normalize_kernel(const float* __restrict__ x, unsigned short* __restrict__ xn) {
    const int row  = blockIdx.x;
    const int lane = threadIdx.x;          // 0..63, 4 elems each
    const float4 v = *(const float4*)(x + (size_t)row * DIM + lane * 4);
    float ss = v.x * v.x + v.y * v.y + v.z * v.z + v.w * v.w;
#pragma unroll
    for (int m = 32; m >= 1; m >>= 1) ss += __shfl_xor(ss, m, 64);
    const float scale = 1.0f / fmaxf(sqrtf(ss), EPS);
    ushort4 o;
    o.x = f2bf(v.x * scale); o.y = f2bf(v.y * scale);
    o.z = f2bf(v.z * scale); o.w = f2bf(v.w * scale);
    *(ushort4*)(xn + (size_t)row * DIM + lane * 4) = o;
}

// ---------------------------------------------------------------------------
// Kernel 2: features fp32 -> (a) fp32 copy into d_out[204800000..], and
//           (b) bf16 copy into ws (rows NS..NPAD zero-padded).
// ---------------------------------------------------------------------------
__global__ __launch_bounds__(256)
void convert_kernel(const float* __restrict__ f, float* __restrict__ fcopy,
                    unsigned short* __restrict__ fb) {
    const long long e = ((long long)blockIdx.x * blockDim.x + threadIdx.x) * 4;
    if (e >= (long long)NPAD * DIM) return;
    if (e < (long long)NS * DIM) {
        const float4 v = *(const float4*)(f + e);
        *(float4*)(fcopy + e) = v;
        ushort4 o;
        o.x = f2bf(v.x); o.y = f2bf(v.y); o.z = f2bf(v.z); o.w = f2bf(v.w);
        *(ushort4*)(fb + e) = o;
    } else {
        ushort4 z; z.x = 0; z.y = 0; z.z = 0; z.w = 0;
        *(ushort4*)(fb + e) = z;
    }
}

// ---------------------------------------------------------------------------
// Kernel 3: C[2048, NS] = A[2048,256](bf16) * B[NPAD,256](bf16)^T, fp32 out.
// m97 structure: 128x128 tile, BK=32, global_load_lds width-16, 4 waves,
// each wave = 64x64 via 4x4 grid of mfma_f32_16x16x32_bf16.
// ---------------------------------------------------------------------------
__global__ __launch_bounds__(256)
void gemm_kernel(const unsigned short* __restrict__ A,   // [2048][256] bf16
                 const unsigned short* __restrict__ Bm,  // [NPAD][256] bf16
                 float* __restrict__ C) {                // [2048][NS] fp32
    __shared__ unsigned short At[BM * BK];   // 8 KB, row-major [128][32]
    __shared__ unsigned short Bt[BN * BK];   // 8 KB

    const int tid  = threadIdx.x;
    const int lane = tid & 63;
    const int wave = tid >> 6;
    const int bm   = blockIdx.x;     // 0..15   (M tiles, fastest -> B-tile reuse)
    const int bn   = blockIdx.y;     // 0..781  (N tiles)

    const int wm   = (wave & 1) * 64;   // wave row offset in tile
    const int wn   = (wave >> 1) * 64;  // wave col offset in tile
    const int quad = lane >> 4;         // 0..3
    const int r    = lane & 15;

    // staging chunk layout: chunk ch in [0,512) covers tile bf16 elements
    // [ch*8, ch*8+8) of the row-major [128][32] tile: m = ch>>2, k = (ch&3)*8.
    const int ch0 = tid;
    const int ch1 = tid + 256;
    const unsigned short* gA0 = A + ((size_t)(bm * BM + (ch0 >> 2)) * DIM) + (ch0 & 3) * 8;
    const unsigned short* gA1 = A + ((size_t)(bm * BM + (ch1 >> 2)) * DIM) + (ch1 & 3) * 8;
    const unsigned short* gB0 = Bm + ((size_t)(bn * BN + (ch0 >> 2)) * DIM) + (ch0 & 3) * 8;
    const unsigned short* gB1 = Bm + ((size_t)(bn * BN + (ch1 >> 2)) * DIM) + (ch1 & 3) * 8;

    f32x4 acc[4][4];
#pragma unroll
    for (int i = 0; i < 4; i++)
#pragma unroll
        for (int j = 0; j < 4; j++) acc[i][j] = (f32x4){0.f, 0.f, 0.f, 0.f};

    for (int kt = 0; kt < DIM; kt += BK) {
        ASYNC_COPY16(gA0 + kt, &At[ch0 * 8]);
        ASYNC_COPY16(gA1 + kt, &At[ch1 * 8]);
        ASYNC_COPY16(gB0 + kt, &Bt[ch0 * 8]);
        ASYNC_COPY16(gB1 + kt, &Bt[ch1 * 8]);
        __syncthreads();   // drains vmcnt before any wave reads LDS

        bf16x8 a[4], b[4];
#pragma unroll
        for (int i = 0; i < 4; i++)
            a[i] = *(const bf16x8*)&At[(wm + i * 16 + r) * BK + quad * 8];
#pragma unroll
        for (int j = 0; j < 4; j++)
            b[j] = *(const bf16x8*)&Bt[(wn + j * 16 + r) * BK + quad * 8];

#pragma unroll
        for (int i = 0; i < 4; i++)
#pragma unroll
            for (int j = 0; j < 4; j++)
                acc[i][j] = __builtin_amdgcn_mfma_f32_16x16x32_bf16(
                    a[i], b[j], acc[i][j], 0, 0, 0);
        __syncthreads();   // before next iter overwrites the tiles
    }

    // Epilogue: C/D layout col = lane&15, row = quad*4 + reg  [m89-verified]
    const int rowbase = bm * BM + wm + quad * 4;
    const int colbase = bn * BN + wn + r;
#pragma unroll
    for (int j = 0; j < 4; j++) {
        const int col = colbase + j * 16;
        if (col < NS) {
#pragma unroll
            for (int i = 0; i < 4; i++) {
#pragma unroll
                for (int g = 0; g < 4; g++) {
                    const int row = rowbase + i * 16 + g;
                    C[(size_t)row * NS + col] = acc[i][j][g];
                }
            }
        }
    }
}

extern "C" void kernel_launch(void* const* d_in, const int* in_sizes, int n_in,
                              void* d_out, int out_size, void* d_ws, size_t ws_size,
                              hipStream_t stream) {
    const float* x        = (const float*)d_in[0];   // [2048,256]
    // d_in[1] = targets (unused by the reference outputs)
    const float* features = (const float*)d_in[2];   // [100000,256]

    float* out0 = (float*)d_out;                      // [2048,100000]
    float* out1 = out0 + (size_t)BROWS * NS;          // features copy [100000,256]

    unsigned short* fb = (unsigned short*)d_ws;               // bf16 features [NPAD,256]
    unsigned short* xn = fb + (size_t)NPAD * DIM;             // bf16 xn [2048,256]

    normalize_kernel<<<BROWS, 64, 0, stream>>>(x, xn);

    const int nvec = (NPAD * DIM) / 4;                // 6,406,144
    convert_kernel<<<nvec / 256, 256, 0, stream>>>(features, out1, fb);

    dim3 grid(BROWS / BM, NPAD / BN);                 // (16, 782)
    gemm_kernel<<<grid, 256, 0, stream>>>(xn, fb, out0);
}